// Round 3
// baseline (716.857 us; speedup 1.0000x reference)
//
#include <hip/hip_runtime.h>
#include <hip/hip_bf16.h>

#define T_SEQ 2048
#define C_DIM 1024
#define H_NUM 16
#define D_HEAD 64
#define B_BATCH 4
#define M_ROWS (B_BATCH * T_SEQ)  // 8192

typedef __attribute__((ext_vector_type(8))) short short8;
typedef __attribute__((ext_vector_type(4))) short short4v;
typedef __attribute__((ext_vector_type(4))) float float4v;
typedef __attribute__((ext_vector_type(4))) int int4v;

static __device__ inline short f2bf(float f) {
    __hip_bfloat16 h = __float2bfloat16(f);
    return *reinterpret_cast<short*>(&h);
}

// ---------------- convert x (fp32 -> bf16), vectorized ----------------
__global__ void k_convert_x(const float* __restrict__ x, short* __restrict__ xb, int n4) {
    int i = blockIdx.x * blockDim.x + threadIdx.x;
    int stride = gridDim.x * blockDim.x;
    for (; i < n4; i += stride) {
        float4v v = reinterpret_cast<const float4v*>(x)[i];
        short4v o;
        o[0] = f2bf(v[0]); o[1] = f2bf(v[1]); o[2] = f2bf(v[2]); o[3] = f2bf(v[3]);
        reinterpret_cast<short4v*>(xb)[i] = o;
    }
}

// ---------------- transpose + convert W (K x N fp32 -> N x K bf16) ----------------
__global__ void k_transpose_w(const float* __restrict__ Wq, const float* __restrict__ Wk,
                              const float* __restrict__ Wv, const float* __restrict__ Wp,
                              short* __restrict__ out) {
    __shared__ float tile[32][33];
    const float* W = (blockIdx.z == 0) ? Wq : (blockIdx.z == 1) ? Wk : (blockIdx.z == 2) ? Wv : Wp;
    short* o = out + (size_t)blockIdx.z * C_DIM * C_DIM;
    int x = blockIdx.x * 32 + threadIdx.x;   // n (col of W)
    int y0 = blockIdx.y * 32;                // k base (row of W)
    for (int i = 0; i < 32; i += 8)
        tile[threadIdx.y + i][threadIdx.x] = W[(size_t)(y0 + threadIdx.y + i) * C_DIM + x];
    __syncthreads();
    int xo = y0 + threadIdx.x;               // k (contiguous in out)
    int yo0 = blockIdx.x * 32;               // n (row of out)
    for (int i = 0; i < 32; i += 8)
        o[(size_t)(yo0 + threadIdx.y + i) * C_DIM + xo] = f2bf(tile[threadIdx.x][threadIdx.y + i]);
}

// ---------------- GEMM: C = A(MxK bf16) @ Bt(NxK bf16)^T + bias ----------------
// MODE 0: -> q (B,H,T,D) bf16, scaled by 0.125
// MODE 1: -> k (B,H,T,D) bf16
// MODE 2: -> vT (B,H,D,T) bf16
// MODE 3: -> out (M,N) fp32
template <int MODE>
__global__ __launch_bounds__(256) void k_gemm(const short* __restrict__ A,
                                              const short* __restrict__ Bt,
                                              const float* __restrict__ bias,
                                              void* __restrict__ outp) {
    __shared__ short As[128][40];
    __shared__ short Bs[128][40];
    const int tid  = threadIdx.x;
    const int lane = tid & 63;
    const int w    = tid >> 6;
    const int wm   = w >> 1, wn = w & 1;
    const int bm   = blockIdx.y, bn = blockIdx.x;
    const int lrow = lane & 15;
    const int kgrp = lane >> 4;

    float4v acc[4][4];
    const float4v fz = {0.f, 0.f, 0.f, 0.f};
    for (int i = 0; i < 4; ++i)
        for (int n = 0; n < 4; ++n) acc[i][n] = fz;

    for (int kt = 0; kt < C_DIM / 32; ++kt) {
#pragma unroll
        for (int s = 0; s < 2; ++s) {
            int cc = tid + s * 256;           // chunk 0..511
            int row = cc >> 2, ko = (cc & 3) * 8;
            int4v va = *reinterpret_cast<const int4v*>(A + (size_t)(bm * 128 + row) * C_DIM + kt * 32 + ko);
            *reinterpret_cast<int4v*>(&As[row][ko]) = va;
            int4v vb = *reinterpret_cast<const int4v*>(Bt + (size_t)(bn * 128 + row) * C_DIM + kt * 32 + ko);
            *reinterpret_cast<int4v*>(&Bs[row][ko]) = vb;
        }
        __syncthreads();
        short8 af[4], bf[4];
#pragma unroll
        for (int i = 0; i < 4; ++i)
            af[i] = *reinterpret_cast<const short8*>(&As[wm * 64 + i * 16 + lrow][kgrp * 8]);
#pragma unroll
        for (int n = 0; n < 4; ++n)
            bf[n] = *reinterpret_cast<const short8*>(&Bs[wn * 64 + n * 16 + lrow][kgrp * 8]);
#pragma unroll
        for (int i = 0; i < 4; ++i)
#pragma unroll
            for (int n = 0; n < 4; ++n)
                acc[i][n] = __builtin_amdgcn_mfma_f32_16x16x32_bf16(af[i], bf[n], acc[i][n], 0, 0, 0);
        __syncthreads();
    }

    int cols[4];
    float bias_v[4];
#pragma unroll
    for (int n = 0; n < 4; ++n) {
        cols[n] = bn * 128 + wn * 64 + n * 16 + lrow;
        bias_v[n] = bias[cols[n]];
    }
#pragma unroll
    for (int i = 0; i < 4; ++i) {
        int m0 = bm * 128 + wm * 64 + i * 16 + kgrp * 4;
#pragma unroll
        for (int n = 0; n < 4; ++n) {
#pragma unroll
            for (int r = 0; r < 4; ++r) {
                float v = acc[i][n][r] + bias_v[n];
                int mm = m0 + r;
                if constexpr (MODE == 3) {
                    reinterpret_cast<float*>(outp)[(size_t)mm * C_DIM + cols[n]] = v;
                } else {
                    int bidx = mm >> 11, t = mm & 2047;
                    int hh = cols[n] >> 6, d = cols[n] & 63;
                    short* o = reinterpret_cast<short*>(outp);
                    if constexpr (MODE == 0) v *= 0.125f;
                    size_t idx;
                    if constexpr (MODE == 2)
                        idx = (((size_t)(bidx * H_NUM + hh)) * D_HEAD + d) * T_SEQ + t;
                    else
                        idx = (((size_t)(bidx * H_NUM + hh)) * T_SEQ + t) * D_HEAD + d;
                    o[idx] = f2bf(v);
                }
            }
        }
    }
}

// ---------------- flash attention: q(B,H,T,D) k(B,H,T,D) vT(B,H,D,T) -> y(B,T,C) ----------------
__global__ __launch_bounds__(256) void k_attn(const short* __restrict__ qb,
                                              const short* __restrict__ kb,
                                              const short* __restrict__ vtb,
                                              short* __restrict__ yb) {
    __shared__ short p_lds[4][16][72];
    const int tid  = threadIdx.x;
    const int lane = tid & 63, w = tid >> 6;
    const int lrow = lane & 15, kgrp = lane >> 4;
    const int bh = blockIdx.y;
    const int q0 = blockIdx.x * 64;
    const int qrow = q0 + w * 16;

    short8 qf[2];
    {
        const short* qbase = qb + ((size_t)bh * T_SEQ + qrow + lrow) * D_HEAD + kgrp * 8;
        qf[0] = *reinterpret_cast<const short8*>(qbase);
        qf[1] = *reinterpret_cast<const short8*>(qbase + 32);
    }

    float m_r[4], l_r[4];
    float4v acc[4];
    const float4v fz = {0.f, 0.f, 0.f, 0.f};
    for (int r = 0; r < 4; ++r) { m_r[r] = -__builtin_huge_valf(); l_r[r] = 0.f; }
    for (int n = 0; n < 4; ++n) acc[n] = fz;

    const int ntiles = blockIdx.x + 1;
    for (int kt = 0; kt < ntiles; ++kt) {
        const int k0 = kt * 64;
        float4v s[4];
        for (int n = 0; n < 4; ++n) s[n] = fz;
        const short* kbase = kb + ((size_t)bh * T_SEQ + k0 + lrow) * D_HEAD + kgrp * 8;
#pragma unroll
        for (int n = 0; n < 4; ++n) {
            const short* kp = kbase + (size_t)n * 16 * D_HEAD;
            short8 kf0 = *reinterpret_cast<const short8*>(kp);
            short8 kf1 = *reinterpret_cast<const short8*>(kp + 32);
            s[n] = __builtin_amdgcn_mfma_f32_16x16x32_bf16(qf[0], kf0, s[n], 0, 0, 0);
            s[n] = __builtin_amdgcn_mfma_f32_16x16x32_bf16(qf[1], kf1, s[n], 0, 0, 0);
        }
        if (kt == blockIdx.x) {  // diagonal tile: causal mask
#pragma unroll
            for (int n = 0; n < 4; ++n) {
                int kabs = k0 + n * 16 + lrow;
#pragma unroll
                for (int r = 0; r < 4; ++r) {
                    int qabs = qrow + kgrp * 4 + r;
                    if (kabs > qabs) s[n][r] = -__builtin_huge_valf();
                }
            }
        }
        float mnew[4], sc[4];
#pragma unroll
        for (int r = 0; r < 4; ++r) {
            float tm = fmaxf(fmaxf(s[0][r], s[1][r]), fmaxf(s[2][r], s[3][r]));
            tm = fmaxf(tm, __shfl_xor(tm, 1));
            tm = fmaxf(tm, __shfl_xor(tm, 2));
            tm = fmaxf(tm, __shfl_xor(tm, 4));
            tm = fmaxf(tm, __shfl_xor(tm, 8));
            mnew[r] = fmaxf(m_r[r], tm);
            sc[r]   = expf(m_r[r] - mnew[r]);
        }
        float rs[4] = {0.f, 0.f, 0.f, 0.f};
#pragma unroll
        for (int n = 0; n < 4; ++n)
#pragma unroll
            for (int r = 0; r < 4; ++r) {
                float p = expf(s[n][r] - mnew[r]);
                s[n][r] = p;
                rs[r] += p;
            }
#pragma unroll
        for (int r = 0; r < 4; ++r) {
            float t = rs[r];
            t += __shfl_xor(t, 1);
            t += __shfl_xor(t, 2);
            t += __shfl_xor(t, 4);
            t += __shfl_xor(t, 8);
            l_r[r] = l_r[r] * sc[r] + t;
            m_r[r] = mnew[r];
        }
#pragma unroll
        for (int n = 0; n < 4; ++n)
#pragma unroll
            for (int r = 0; r < 4; ++r) acc[n][r] *= sc[r];

        __syncthreads();
#pragma unroll
        for (int n = 0; n < 4; ++n)
#pragma unroll
            for (int r = 0; r < 4; ++r)
                p_lds[w][kgrp * 4 + r][n * 16 + lrow] = f2bf(s[n][r]);
        __syncthreads();

        short8 pa[2];
        pa[0] = *reinterpret_cast<const short8*>(&p_lds[w][lrow][kgrp * 8]);
        pa[1] = *reinterpret_cast<const short8*>(&p_lds[w][lrow][32 + kgrp * 8]);
        const short* vbase = vtb + ((size_t)bh * D_HEAD + lrow) * T_SEQ + k0 + kgrp * 8;
#pragma unroll
        for (int n = 0; n < 4; ++n) {
            const short* vp = vbase + (size_t)n * 16 * T_SEQ;
            short8 vf0 = *reinterpret_cast<const short8*>(vp);
            short8 vf1 = *reinterpret_cast<const short8*>(vp + 32);
            acc[n] = __builtin_amdgcn_mfma_f32_16x16x32_bf16(pa[0], vf0, acc[n], 0, 0, 0);
            acc[n] = __builtin_amdgcn_mfma_f32_16x16x32_bf16(pa[1], vf1, acc[n], 0, 0, 0);
        }
    }

    const int b = bh >> 4, h = bh & 15;
#pragma unroll
    for (int r = 0; r < 4; ++r) {
        float inv = 1.0f / l_r[r];
        int t = qrow + kgrp * 4 + r;
        size_t base = ((size_t)b * T_SEQ + t) * C_DIM + h * D_HEAD;
#pragma unroll
        for (int n = 0; n < 4; ++n)
            yb[base + n * 16 + lrow] = f2bf(acc[n][r] * inv);
    }
}

extern "C" void kernel_launch(void* const* d_in, const int* in_sizes, int n_in,
                              void* d_out, int out_size, void* d_ws, size_t ws_size,
                              hipStream_t stream) {
    const float* x  = (const float*)d_in[0];
    const float* Wq = (const float*)d_in[1];
    const float* bq = (const float*)d_in[2];
    const float* Wk = (const float*)d_in[3];
    const float* bk = (const float*)d_in[4];
    const float* Wv = (const float*)d_in[5];
    const float* bv = (const float*)d_in[6];
    const float* Wp = (const float*)d_in[7];
    const float* bp = (const float*)d_in[8];

    char* ws = (char*)d_ws;
    short* xb = (short*)(ws);                        // 16 MiB (reused as y after projections)
    short* wt = (short*)(ws + (size_t)(16 << 20));   // 8 MiB (4 transposed bf16 weights)
    short* qb = (short*)(ws + (size_t)(24 << 20));   // 16 MiB
    short* kb = (short*)(ws + (size_t)(40 << 20));   // 16 MiB
    short* vt = (short*)(ws + (size_t)(56 << 20));   // 16 MiB; total 72 MiB

    k_convert_x<<<2048, 256, 0, stream>>>(x, xb, M_ROWS * C_DIM / 4);
    k_transpose_w<<<dim3(32, 32, 4), dim3(32, 8), 0, stream>>>(Wq, Wk, Wv, Wp, wt);

    k_gemm<0><<<dim3(8, 64), 256, 0, stream>>>(xb, wt,                bq, (void*)qb);
    k_gemm<1><<<dim3(8, 64), 256, 0, stream>>>(xb, wt + (1u << 20),   bk, (void*)kb);
    k_gemm<2><<<dim3(8, 64), 256, 0, stream>>>(xb, wt + (2u << 20),   bv, (void*)vt);

    k_attn<<<dim3(32, 64), 256, 0, stream>>>(qb, kb, vt, xb);

    k_gemm<3><<<dim3(8, 64), 256, 0, stream>>>(xb, wt + (3u << 20), bp, d_out);
}

// Round 8
// 665.883 us; speedup vs baseline: 1.0766x; 1.0766x over previous
//
#include <hip/hip_runtime.h>
#include <hip/hip_bf16.h>

#define T_SEQ 2048
#define C_DIM 1024
#define H_NUM 16
#define D_HEAD 64
#define B_BATCH 4
#define M_ROWS (B_BATCH * T_SEQ)  // 8192

typedef __attribute__((ext_vector_type(8))) short short8;
typedef __attribute__((ext_vector_type(4))) short short4v;
typedef __attribute__((ext_vector_type(4))) float float4v;
typedef __attribute__((ext_vector_type(4))) int int4v;

// global_load_lds: LDS dest = wave-uniform base + lane*16; global src is per-lane.
#define GLOAD_LDS16(gp, lp)                                                              \
    __builtin_amdgcn_global_load_lds(                                                    \
        (const __attribute__((address_space(1))) void*)(gp),                             \
        (__attribute__((address_space(3))) void*)(lp), 16, 0, 0)

static __device__ inline short f2bf(float f) {
    __hip_bfloat16 h = __float2bfloat16(f);
    return *reinterpret_cast<short*>(&h);
}

// ---------------- convert x (fp32 -> bf16), vectorized ----------------
__global__ void k_convert_x(const float* __restrict__ x, short* __restrict__ xb, int n4) {
    int i = blockIdx.x * blockDim.x + threadIdx.x;
    int stride = gridDim.x * blockDim.x;
    for (; i < n4; i += stride) {
        float4v v = reinterpret_cast<const float4v*>(x)[i];
        short4v o;
        o[0] = f2bf(v[0]); o[1] = f2bf(v[1]); o[2] = f2bf(v[2]); o[3] = f2bf(v[3]);
        reinterpret_cast<short4v*>(xb)[i] = o;
    }
}

// ---------------- transpose + convert W (K x N fp32 -> N x K bf16) ----------------
__global__ void k_transpose_w(const float* __restrict__ Wq, const float* __restrict__ Wk,
                              const float* __restrict__ Wv, const float* __restrict__ Wp,
                              short* __restrict__ out) {
    __shared__ float tile[32][33];
    const float* W = (blockIdx.z == 0) ? Wq : (blockIdx.z == 1) ? Wk : (blockIdx.z == 2) ? Wv : Wp;
    short* o = out + (size_t)blockIdx.z * C_DIM * C_DIM;
    int x = blockIdx.x * 32 + threadIdx.x;   // n (col of W)
    int y0 = blockIdx.y * 32;                // k base (row of W)
    for (int i = 0; i < 32; i += 8)
        tile[threadIdx.y + i][threadIdx.x] = W[(size_t)(y0 + threadIdx.y + i) * C_DIM + x];
    __syncthreads();
    int xo = y0 + threadIdx.x;               // k (contiguous in out)
    int yo0 = blockIdx.x * 32;               // n (row of out)
    for (int i = 0; i < 32; i += 8)
        o[(size_t)(yo0 + threadIdx.y + i) * C_DIM + xo] = f2bf(tile[threadIdx.x][threadIdx.y + i]);
}

// ---------------- GEMM: C = A(MxK bf16) @ Bt(NxK bf16)^T + bias ----------------
// m97-style staging: global_load_lds width-16, linear LDS (no pad), 2-barrier loop.
// MODE 0: -> q (B,H,T,D) bf16, scaled by 0.125*log2(e)  [folds softmax exp2 conversion]
// MODE 1: -> k (B,H,T,D) bf16
// MODE 2: -> vT (B,H,D,T) bf16
// MODE 3: -> out (M,N) fp32
template <int MODE>
__global__ __launch_bounds__(256) void k_gemm(const short* __restrict__ A,
                                              const short* __restrict__ Bt,
                                              const float* __restrict__ bias,
                                              void* __restrict__ outp) {
    __shared__ short As[128][32];   // 8 KiB, linear (global_load_lds requires contiguous dest)
    __shared__ short Bs[128][32];   // 8 KiB
    const int tid  = threadIdx.x;
    const int lane = tid & 63;
    const int w    = tid >> 6;
    const int wm   = w >> 1, wn = w & 1;
    const int bm   = blockIdx.y, bn = blockIdx.x;
    const int lrow = lane & 15;
    const int kgrp = lane >> 4;

    // staging geometry: one issue = 64 lanes * 16B = 1 KiB = 16 rows of [32] bf16.
    // wave w covers rows w*32 .. w*32+31 (2 issues) for each of As, Bs.
    const int srow = lane >> 2;          // 0..15 row within issue
    const int scol = (lane & 3) * 8;     // shorts
    const short* gA = A  + (size_t)(bm * 128 + w * 32 + srow) * C_DIM + scol;
    const short* gB = Bt + (size_t)(bn * 128 + w * 32 + srow) * C_DIM + scol;
    short* lA0 = &As[w * 32][0];
    short* lA1 = &As[w * 32 + 16][0];
    short* lB0 = &Bs[w * 32][0];
    short* lB1 = &Bs[w * 32 + 16][0];

    float4v acc[4][4];
    const float4v fz = {0.f, 0.f, 0.f, 0.f};
    for (int i = 0; i < 4; ++i)
        for (int n = 0; n < 4; ++n) acc[i][n] = fz;

    for (int kt = 0; kt < C_DIM / 32; ++kt) {
        const int ko = kt * 32;
        GLOAD_LDS16(gA + ko,               lA0);
        GLOAD_LDS16(gA + ko + 16 * C_DIM, lA1);
        GLOAD_LDS16(gB + ko,               lB0);
        GLOAD_LDS16(gB + ko + 16 * C_DIM, lB1);
        __syncthreads();   // compiler emits vmcnt(0) drain before barrier
        short8 af[4], bf[4];
#pragma unroll
        for (int i = 0; i < 4; ++i)
            af[i] = *reinterpret_cast<const short8*>(&As[wm * 64 + i * 16 + lrow][kgrp * 8]);
#pragma unroll
        for (int n = 0; n < 4; ++n)
            bf[n] = *reinterpret_cast<const short8*>(&Bs[wn * 64 + n * 16 + lrow][kgrp * 8]);
#pragma unroll
        for (int i = 0; i < 4; ++i)
#pragma unroll
            for (int n = 0; n < 4; ++n)
                acc[i][n] = __builtin_amdgcn_mfma_f32_16x16x32_bf16(af[i], bf[n], acc[i][n], 0, 0, 0);
        __syncthreads();
    }

    int cols[4];
    float bias_v[4];
#pragma unroll
    for (int n = 0; n < 4; ++n) {
        cols[n] = bn * 128 + wn * 64 + n * 16 + lrow;
        bias_v[n] = bias[cols[n]];
    }
#pragma unroll
    for (int i = 0; i < 4; ++i) {
        int m0 = bm * 128 + wm * 64 + i * 16 + kgrp * 4;
#pragma unroll
        for (int n = 0; n < 4; ++n) {
#pragma unroll
            for (int r = 0; r < 4; ++r) {
                float v = acc[i][n][r] + bias_v[n];
                int mm = m0 + r;
                if constexpr (MODE == 3) {
                    reinterpret_cast<float*>(outp)[(size_t)mm * C_DIM + cols[n]] = v;
                } else {
                    int bidx = mm >> 11, t = mm & 2047;
                    int hh = cols[n] >> 6, d = cols[n] & 63;
                    short* o = reinterpret_cast<short*>(outp);
                    if constexpr (MODE == 0) v *= 0.18033688f;  // 0.125 * log2(e)
                    size_t idx;
                    if constexpr (MODE == 2)
                        idx = (((size_t)(bidx * H_NUM + hh)) * D_HEAD + d) * T_SEQ + t;
                    else
                        idx = (((size_t)(bidx * H_NUM + hh)) * T_SEQ + t) * D_HEAD + d;
                    o[idx] = f2bf(v);
                }
            }
        }
    }
}

// ---------------- flash attention: q(B,H,T,D) k(B,H,T,D) vT(B,H,D,T) -> y(B,T,C) ----------------
// v2: LPT block order (heavy q-tiles first), no barriers (p_lds is wave-private),
// exp2-domain softmax (log2e folded into q), V loads hoisted under softmax.
__global__ __launch_bounds__(256) void k_attn(const short* __restrict__ qb,
                                              const short* __restrict__ kb,
                                              const short* __restrict__ vtb,
                                              short* __restrict__ yb) {
    __shared__ short p_lds[4][16][72];
    const int tid  = threadIdx.x;
    const int lane = tid & 63, w = tid >> 6;
    const int lrow = lane & 15, kgrp = lane >> 4;
    const int bh = blockIdx.y;
    const int qj = 31 - blockIdx.x;          // LPT: heavy blocks dispatch first
    const int q0 = qj * 64;
    const int qrow = q0 + w * 16;

    short8 qf[2];
    {
        const short* qbase = qb + ((size_t)bh * T_SEQ + qrow + lrow) * D_HEAD + kgrp * 8;
        qf[0] = *reinterpret_cast<const short8*>(qbase);
        qf[1] = *reinterpret_cast<const short8*>(qbase + 32);
    }

    float m_r[4], l_r[4];
    float4v acc[4];
    const float4v fz = {0.f, 0.f, 0.f, 0.f};
    for (int r = 0; r < 4; ++r) { m_r[r] = -__builtin_huge_valf(); l_r[r] = 0.f; }
    for (int n = 0; n < 4; ++n) acc[n] = fz;

    const int ntiles = qj + 1;
    for (int kt = 0; kt < ntiles; ++kt) {
        const int k0 = kt * 64;
        float4v s[4];
        for (int n = 0; n < 4; ++n) s[n] = fz;
        const short* kbase = kb + ((size_t)bh * T_SEQ + k0 + lrow) * D_HEAD + kgrp * 8;
#pragma unroll
        for (int n = 0; n < 4; ++n) {
            const short* kp = kbase + (size_t)n * 16 * D_HEAD;
            short8 kf0 = *reinterpret_cast<const short8*>(kp);
            short8 kf1 = *reinterpret_cast<const short8*>(kp + 32);
            s[n] = __builtin_amdgcn_mfma_f32_16x16x32_bf16(qf[0], kf0, s[n], 0, 0, 0);
            s[n] = __builtin_amdgcn_mfma_f32_16x16x32_bf16(qf[1], kf1, s[n], 0, 0, 0);
        }
        // V loads issued NOW — latency hides under mask+softmax
        const short* vbase = vtb + ((size_t)bh * D_HEAD + lrow) * T_SEQ + k0 + kgrp * 8;
        short8 vf0[4], vf1[4];
#pragma unroll
        for (int n = 0; n < 4; ++n) {
            const short* vp = vbase + (size_t)n * 16 * T_SEQ;
            vf0[n] = *reinterpret_cast<const short8*>(vp);
            vf1[n] = *reinterpret_cast<const short8*>(vp + 32);
        }
        if (kt == ntiles - 1) {  // diagonal tile: causal mask
#pragma unroll
            for (int n = 0; n < 4; ++n) {
                int kabs = k0 + n * 16 + lrow;
#pragma unroll
                for (int r = 0; r < 4; ++r) {
                    int qabs = qrow + kgrp * 4 + r;
                    if (kabs > qabs) s[n][r] = -__builtin_huge_valf();
                }
            }
        }
        // scores are in log2-units (log2e folded into q); all exp -> exp2 (1 inst)
        float mnew[4], sc[4];
#pragma unroll
        for (int r = 0; r < 4; ++r) {
            float tm = fmaxf(fmaxf(s[0][r], s[1][r]), fmaxf(s[2][r], s[3][r]));
            tm = fmaxf(tm, __shfl_xor(tm, 1));
            tm = fmaxf(tm, __shfl_xor(tm, 2));
            tm = fmaxf(tm, __shfl_xor(tm, 4));
            tm = fmaxf(tm, __shfl_xor(tm, 8));
            mnew[r] = fmaxf(m_r[r], tm);
            sc[r]   = exp2f(m_r[r] - mnew[r]);
        }
        float rs[4] = {0.f, 0.f, 0.f, 0.f};
#pragma unroll
        for (int n = 0; n < 4; ++n)
#pragma unroll
            for (int r = 0; r < 4; ++r) {
                float p = exp2f(s[n][r] - mnew[r]);
                s[n][r] = p;
                rs[r] += p;
            }
#pragma unroll
        for (int r = 0; r < 4; ++r) {
            float t = rs[r];
            t += __shfl_xor(t, 1);
            t += __shfl_xor(t, 2);
            t += __shfl_xor(t, 4);
            t += __shfl_xor(t, 8);
            l_r[r] = l_r[r] * sc[r] + t;
            m_r[r] = mnew[r];
        }
#pragma unroll
        for (int n = 0; n < 4; ++n)
#pragma unroll
            for (int r = 0; r < 4; ++r) acc[n][r] *= sc[r];

        // p_lds[w] is wave-private: no __syncthreads needed (intra-wave lgkmcnt ordering)
#pragma unroll
        for (int n = 0; n < 4; ++n)
#pragma unroll
            for (int r = 0; r < 4; ++r)
                p_lds[w][kgrp * 4 + r][n * 16 + lrow] = f2bf(s[n][r]);

        short8 pa[2];
        pa[0] = *reinterpret_cast<const short8*>(&p_lds[w][lrow][kgrp * 8]);
        pa[1] = *reinterpret_cast<const short8*>(&p_lds[w][lrow][32 + kgrp * 8]);
#pragma unroll
        for (int n = 0; n < 4; ++n) {
            acc[n] = __builtin_amdgcn_mfma_f32_16x16x32_bf16(pa[0], vf0[n], acc[n], 0, 0, 0);
            acc[n] = __builtin_amdgcn_mfma_f32_16x16x32_bf16(pa[1], vf1[n], acc[n], 0, 0, 0);
        }
    }

    const int b = bh >> 4, h = bh & 15;
#pragma unroll
    for (int r = 0; r < 4; ++r) {
        float inv = 1.0f / l_r[r];
        int t = qrow + kgrp * 4 + r;
        size_t base = ((size_t)b * T_SEQ + t) * C_DIM + h * D_HEAD;
#pragma unroll
        for (int n = 0; n < 4; ++n)
            yb[base + n * 16 + lrow] = f2bf(acc[n][r] * inv);
    }
}

extern "C" void kernel_launch(void* const* d_in, const int* in_sizes, int n_in,
                              void* d_out, int out_size, void* d_ws, size_t ws_size,
                              hipStream_t stream) {
    const float* x  = (const float*)d_in[0];
    const float* Wq = (const float*)d_in[1];
    const float* bq = (const float*)d_in[2];
    const float* Wk = (const float*)d_in[3];
    const float* bk = (const float*)d_in[4];
    const float* Wv = (const float*)d_in[5];
    const float* bv = (const float*)d_in[6];
    const float* Wp = (const float*)d_in[7];
    const float* bp = (const float*)d_in[8];

    char* ws = (char*)d_ws;
    short* xb = (short*)(ws);                        // 16 MiB (reused as y after attention)
    short* wt = (short*)(ws + (size_t)(16 << 20));   // 8 MiB (4 transposed bf16 weights)
    short* qb = (short*)(ws + (size_t)(24 << 20));   // 16 MiB
    short* kb = (short*)(ws + (size_t)(40 << 20));   // 16 MiB
    short* vt = (short*)(ws + (size_t)(56 << 20));   // 16 MiB; total 72 MiB

    k_convert_x<<<2048, 256, 0, stream>>>(x, xb, M_ROWS * C_DIM / 4);
    k_transpose_w<<<dim3(32, 32, 4), dim3(32, 8), 0, stream>>>(Wq, Wk, Wv, Wp, wt);

    k_gemm<0><<<dim3(8, 64), 256, 0, stream>>>(xb, wt,                bq, (void*)qb);
    k_gemm<1><<<dim3(8, 64), 256, 0, stream>>>(xb, wt + (1u << 20),   bk, (void*)kb);
    k_gemm<2><<<dim3(8, 64), 256, 0, stream>>>(xb, wt + (2u << 20),   bv, (void*)vt);

    k_attn<<<dim3(32, 64), 256, 0, stream>>>(qb, kb, vt, xb);

    k_gemm<3><<<dim3(8, 64), 256, 0, stream>>>(xb, wt + (3u << 20), bp, d_out);
}

// Round 12
// 490.517 us; speedup vs baseline: 1.4614x; 1.3575x over previous
//
#include <hip/hip_runtime.h>
#include <hip/hip_bf16.h>

#define T_SEQ 2048
#define C_DIM 1024
#define H_NUM 16
#define D_HEAD 64
#define B_BATCH 4
#define M_ROWS (B_BATCH * T_SEQ)  // 8192

typedef __attribute__((ext_vector_type(8))) short short8;
typedef __attribute__((ext_vector_type(4))) short short4v;
typedef __attribute__((ext_vector_type(4))) float float4v;
typedef __attribute__((ext_vector_type(4))) int int4v;

// global_load_lds: LDS dest = wave-uniform base + lane*16; global src is per-lane.
#define GLOAD_LDS16(gp, lp)                                                              \
    __builtin_amdgcn_global_load_lds(                                                    \
        (const __attribute__((address_space(1))) void*)(gp),                             \
        (__attribute__((address_space(3))) void*)(lp), 16, 0, 0)

static __device__ inline short f2bf(float f) {
    __hip_bfloat16 h = __float2bfloat16(f);
    return *reinterpret_cast<short*>(&h);
}

// ---------------- convert x (fp32 -> bf16), vectorized ----------------
__global__ void k_convert_x(const float* __restrict__ x, short* __restrict__ xb, int n4) {
    int i = blockIdx.x * blockDim.x + threadIdx.x;
    int stride = gridDim.x * blockDim.x;
    for (; i < n4; i += stride) {
        float4v v = reinterpret_cast<const float4v*>(x)[i];
        short4v o;
        o[0] = f2bf(v[0]); o[1] = f2bf(v[1]); o[2] = f2bf(v[2]); o[3] = f2bf(v[3]);
        reinterpret_cast<short4v*>(xb)[i] = o;
    }
}

// ---------------- transpose + convert W (K x N fp32 -> N x K bf16) ----------------
__global__ void k_transpose_w(const float* __restrict__ Wq, const float* __restrict__ Wk,
                              const float* __restrict__ Wv, const float* __restrict__ Wp,
                              short* __restrict__ out) {
    __shared__ float tile[32][33];
    const float* W = (blockIdx.z == 0) ? Wq : (blockIdx.z == 1) ? Wk : (blockIdx.z == 2) ? Wv : Wp;
    short* o = out + (size_t)blockIdx.z * C_DIM * C_DIM;
    int x = blockIdx.x * 32 + threadIdx.x;   // n (col of W)
    int y0 = blockIdx.y * 32;                // k base (row of W)
    for (int i = 0; i < 32; i += 8)
        tile[threadIdx.y + i][threadIdx.x] = W[(size_t)(y0 + threadIdx.y + i) * C_DIM + x];
    __syncthreads();
    int xo = y0 + threadIdx.x;               // k (contiguous in out)
    int yo0 = blockIdx.x * 32;               // n (row of out)
    for (int i = 0; i < 32; i += 8)
        o[(size_t)(yo0 + threadIdx.y + i) * C_DIM + xo] = f2bf(tile[threadIdx.x][threadIdx.y + i]);
}

// ---------------- GEMM: C = A(MxK bf16) @ Bt(NxK bf16)^T + bias ----------------
// m97-style staging: global_load_lds width-16, linear LDS (no pad), 2-barrier loop.
// MODE 0: -> q (B,H,T,D) bf16, scaled by 0.125*log2(e)  [folds softmax exp2 conversion]
// MODE 1: -> k (B,H,T,D) bf16
// MODE 2: -> vT (B,H,D,T) bf16
// MODE 3: -> out (M,N) fp32
template <int MODE>
__global__ __launch_bounds__(256) void k_gemm(const short* __restrict__ A,
                                              const short* __restrict__ Bt,
                                              const float* __restrict__ bias,
                                              void* __restrict__ outp) {
    __shared__ short As[128][32];   // 8 KiB, linear (global_load_lds requires contiguous dest)
    __shared__ short Bs[128][32];   // 8 KiB
    const int tid  = threadIdx.x;
    const int lane = tid & 63;
    const int w    = tid >> 6;
    const int wm   = w >> 1, wn = w & 1;
    const int bm   = blockIdx.y, bn = blockIdx.x;
    const int lrow = lane & 15;
    const int kgrp = lane >> 4;

    // staging geometry: one issue = 64 lanes * 16B = 1 KiB = 16 rows of [32] bf16.
    // wave w covers rows w*32 .. w*32+31 (2 issues) for each of As, Bs.
    const int srow = lane >> 2;          // 0..15 row within issue
    const int scol = (lane & 3) * 8;     // shorts
    const short* gA = A  + (size_t)(bm * 128 + w * 32 + srow) * C_DIM + scol;
    const short* gB = Bt + (size_t)(bn * 128 + w * 32 + srow) * C_DIM + scol;
    short* lA0 = &As[w * 32][0];
    short* lA1 = &As[w * 32 + 16][0];
    short* lB0 = &Bs[w * 32][0];
    short* lB1 = &Bs[w * 32 + 16][0];

    float4v acc[4][4];
    const float4v fz = {0.f, 0.f, 0.f, 0.f};
    for (int i = 0; i < 4; ++i)
        for (int n = 0; n < 4; ++n) acc[i][n] = fz;

    for (int kt = 0; kt < C_DIM / 32; ++kt) {
        const int ko = kt * 32;
        GLOAD_LDS16(gA + ko,               lA0);
        GLOAD_LDS16(gA + ko + 16 * C_DIM, lA1);
        GLOAD_LDS16(gB + ko,               lB0);
        GLOAD_LDS16(gB + ko + 16 * C_DIM, lB1);
        __syncthreads();   // compiler emits vmcnt(0) drain before barrier
        short8 af[4], bf[4];
#pragma unroll
        for (int i = 0; i < 4; ++i)
            af[i] = *reinterpret_cast<const short8*>(&As[wm * 64 + i * 16 + lrow][kgrp * 8]);
#pragma unroll
        for (int n = 0; n < 4; ++n)
            bf[n] = *reinterpret_cast<const short8*>(&Bs[wn * 64 + n * 16 + lrow][kgrp * 8]);
#pragma unroll
        for (int i = 0; i < 4; ++i)
#pragma unroll
            for (int n = 0; n < 4; ++n)
                acc[i][n] = __builtin_amdgcn_mfma_f32_16x16x32_bf16(af[i], bf[n], acc[i][n], 0, 0, 0);
        __syncthreads();
    }

    int cols[4];
    float bias_v[4];
#pragma unroll
    for (int n = 0; n < 4; ++n) {
        cols[n] = bn * 128 + wn * 64 + n * 16 + lrow;
        bias_v[n] = bias[cols[n]];
    }
#pragma unroll
    for (int i = 0; i < 4; ++i) {
        int m0 = bm * 128 + wm * 64 + i * 16 + kgrp * 4;
#pragma unroll
        for (int n = 0; n < 4; ++n) {
#pragma unroll
            for (int r = 0; r < 4; ++r) {
                float v = acc[i][n][r] + bias_v[n];
                int mm = m0 + r;
                if constexpr (MODE == 3) {
                    reinterpret_cast<float*>(outp)[(size_t)mm * C_DIM + cols[n]] = v;
                } else {
                    int bidx = mm >> 11, t = mm & 2047;
                    int hh = cols[n] >> 6, d = cols[n] & 63;
                    short* o = reinterpret_cast<short*>(outp);
                    if constexpr (MODE == 0) v *= 0.18033688f;  // 0.125 * log2(e)
                    size_t idx;
                    if constexpr (MODE == 2)
                        idx = (((size_t)(bidx * H_NUM + hh)) * D_HEAD + d) * T_SEQ + t;
                    else
                        idx = (((size_t)(bidx * H_NUM + hh)) * T_SEQ + t) * D_HEAD + d;
                    o[idx] = f2bf(v);
                }
            }
        }
    }
}

// ---------------- flash attention: q(B,H,T,D) k(B,H,T,D) vT(B,H,D,T) -> y(B,T,C) ----------------
// v3: balanced q-tile PAIRS per block (qj = 31-bx then bx: constant 33 k-iters/block,
// grid 16x64 = constant residency, no decay tail), per-lane deferred l-sum (no in-loop
// sum shfl chain), defer-max rescale skip (THR=8 in log2 units; bf16 is scale-free),
// exp2-domain softmax, hoisted V loads, wave-private P LDS (no barriers).
__global__ __launch_bounds__(256) void k_attn(const short* __restrict__ qb,
                                              const short* __restrict__ kb,
                                              const short* __restrict__ vtb,
                                              short* __restrict__ yb) {
    __shared__ short p_lds[4][16][72];
    const int tid  = threadIdx.x;
    const int lane = tid & 63, w = tid >> 6;
    const int lrow = lane & 15, kgrp = lane >> 4;
    const int bh = blockIdx.y;
    const int b = bh >> 4, h = bh & 15;
    const float4v fz = {0.f, 0.f, 0.f, 0.f};
    const float THR = 8.0f;

#pragma unroll 1
    for (int phase = 0; phase < 2; ++phase) {
        const int qj = (phase == 0) ? (31 - (int)blockIdx.x) : (int)blockIdx.x;
        const int q0 = qj * 64;
        const int qrow = q0 + w * 16;

        short8 qf[2];
        {
            const short* qbase = qb + ((size_t)bh * T_SEQ + qrow + lrow) * D_HEAD + kgrp * 8;
            qf[0] = *reinterpret_cast<const short8*>(qbase);
            qf[1] = *reinterpret_cast<const short8*>(qbase + 32);
        }

        float m_r[4], l_p[4];   // running max (log2 units), per-lane partial denom
        float4v acc[4];
        for (int r = 0; r < 4; ++r) { m_r[r] = -__builtin_huge_valf(); l_p[r] = 0.f; }
        for (int n = 0; n < 4; ++n) acc[n] = fz;

        const int ntiles = qj + 1;
        for (int kt = 0; kt < ntiles; ++kt) {
            const int k0 = kt * 64;
            float4v s[4];
            for (int n = 0; n < 4; ++n) s[n] = fz;
            const short* kbase = kb + ((size_t)bh * T_SEQ + k0 + lrow) * D_HEAD + kgrp * 8;
#pragma unroll
            for (int n = 0; n < 4; ++n) {
                const short* kp = kbase + (size_t)n * 16 * D_HEAD;
                short8 kf0 = *reinterpret_cast<const short8*>(kp);
                short8 kf1 = *reinterpret_cast<const short8*>(kp + 32);
                s[n] = __builtin_amdgcn_mfma_f32_16x16x32_bf16(qf[0], kf0, s[n], 0, 0, 0);
                s[n] = __builtin_amdgcn_mfma_f32_16x16x32_bf16(qf[1], kf1, s[n], 0, 0, 0);
            }
            // V loads issued NOW — latency hides under mask+softmax
            const short* vbase = vtb + ((size_t)bh * D_HEAD + lrow) * T_SEQ + k0 + kgrp * 8;
            short8 vf0[4], vf1[4];
#pragma unroll
            for (int n = 0; n < 4; ++n) {
                const short* vp = vbase + (size_t)n * 16 * T_SEQ;
                vf0[n] = *reinterpret_cast<const short8*>(vp);
                vf1[n] = *reinterpret_cast<const short8*>(vp + 32);
            }
            if (kt == ntiles - 1) {  // diagonal tile: causal mask
#pragma unroll
                for (int n = 0; n < 4; ++n) {
                    int kabs = k0 + n * 16 + lrow;
#pragma unroll
                    for (int r = 0; r < 4; ++r) {
                        int qabs = qrow + kgrp * 4 + r;
                        if (kabs > qabs) s[n][r] = -__builtin_huge_valf();
                    }
                }
            }
            // row max (only shfl chain left in the loop)
            float tm[4];
#pragma unroll
            for (int r = 0; r < 4; ++r) {
                float t = fmaxf(fmaxf(s[0][r], s[1][r]), fmaxf(s[2][r], s[3][r]));
                t = fmaxf(t, __shfl_xor(t, 1));
                t = fmaxf(t, __shfl_xor(t, 2));
                t = fmaxf(t, __shfl_xor(t, 4));
                t = fmaxf(t, __shfl_xor(t, 8));
                tm[r] = t;
            }
            // defer-max: rescale only when some row's max grew past m + THR
            int grow = (tm[0] > m_r[0] + THR) | (tm[1] > m_r[1] + THR) |
                       (tm[2] > m_r[2] + THR) | (tm[3] > m_r[3] + THR);
            if (__any(grow)) {
#pragma unroll
                for (int r = 0; r < 4; ++r) {
                    float mnew = fmaxf(m_r[r], tm[r]);
                    float sc = exp2f(m_r[r] - mnew);
                    m_r[r] = mnew;
                    l_p[r] *= sc;
#pragma unroll
                    for (int n = 0; n < 4; ++n) acc[n][r] *= sc;
                }
            }
            // P = exp2(s - m); per-lane partial row sums (no shfl)
#pragma unroll
            for (int n = 0; n < 4; ++n)
#pragma unroll
                for (int r = 0; r < 4; ++r) {
                    float p = exp2f(s[n][r] - m_r[r]);
                    s[n][r] = p;
                    l_p[r] += p;
                }

            // p_lds[w] is wave-private: no __syncthreads needed (intra-wave lgkmcnt ordering)
#pragma unroll
            for (int n = 0; n < 4; ++n)
#pragma unroll
                for (int r = 0; r < 4; ++r)
                    p_lds[w][kgrp * 4 + r][n * 16 + lrow] = f2bf(s[n][r]);

            short8 pa[2];
            pa[0] = *reinterpret_cast<const short8*>(&p_lds[w][lrow][kgrp * 8]);
            pa[1] = *reinterpret_cast<const short8*>(&p_lds[w][lrow][32 + kgrp * 8]);
#pragma unroll
            for (int n = 0; n < 4; ++n) {
                acc[n] = __builtin_amdgcn_mfma_f32_16x16x32_bf16(pa[0], vf0[n], acc[n], 0, 0, 0);
                acc[n] = __builtin_amdgcn_mfma_f32_16x16x32_bf16(pa[1], vf1[n], acc[n], 0, 0, 0);
            }
        }

        // final denom reduce (once per phase, not per tile)
#pragma unroll
        for (int r = 0; r < 4; ++r) {
            float t = l_p[r];
            t += __shfl_xor(t, 1);
            t += __shfl_xor(t, 2);
            t += __shfl_xor(t, 4);
            t += __shfl_xor(t, 8);
            float inv = 1.0f / t;
            int trow = qrow + kgrp * 4 + r;
            size_t base = ((size_t)b * T_SEQ + trow) * C_DIM + h * D_HEAD;
#pragma unroll
            for (int n = 0; n < 4; ++n)
                yb[base + n * 16 + lrow] = f2bf(acc[n][r] * inv);
        }
    }
}

extern "C" void kernel_launch(void* const* d_in, const int* in_sizes, int n_in,
                              void* d_out, int out_size, void* d_ws, size_t ws_size,
                              hipStream_t stream) {
    const float* x  = (const float*)d_in[0];
    const float* Wq = (const float*)d_in[1];
    const float* bq = (const float*)d_in[2];
    const float* Wk = (const float*)d_in[3];
    const float* bk = (const float*)d_in[4];
    const float* Wv = (const float*)d_in[5];
    const float* bv = (const float*)d_in[6];
    const float* Wp = (const float*)d_in[7];
    const float* bp = (const float*)d_in[8];

    char* ws = (char*)d_ws;
    short* xb = (short*)(ws);                        // 16 MiB (reused as y after attention)
    short* wt = (short*)(ws + (size_t)(16 << 20));   // 8 MiB (4 transposed bf16 weights)
    short* qb = (short*)(ws + (size_t)(24 << 20));   // 16 MiB
    short* kb = (short*)(ws + (size_t)(40 << 20));   // 16 MiB
    short* vt = (short*)(ws + (size_t)(56 << 20));   // 16 MiB; total 72 MiB

    k_convert_x<<<2048, 256, 0, stream>>>(x, xb, M_ROWS * C_DIM / 4);
    k_transpose_w<<<dim3(32, 32, 4), dim3(32, 8), 0, stream>>>(Wq, Wk, Wv, Wp, wt);

    k_gemm<0><<<dim3(8, 64), 256, 0, stream>>>(xb, wt,                bq, (void*)qb);
    k_gemm<1><<<dim3(8, 64), 256, 0, stream>>>(xb, wt + (1u << 20),   bk, (void*)kb);
    k_gemm<2><<<dim3(8, 64), 256, 0, stream>>>(xb, wt + (2u << 20),   bv, (void*)vt);

    k_attn<<<dim3(16, 64), 256, 0, stream>>>(qb, kb, vt, xb);

    k_gemm<3><<<dim3(8, 64), 256, 0, stream>>>(xb, wt + (3u << 20), bp, d_out);
}

// Round 13
// 484.761 us; speedup vs baseline: 1.4788x; 1.0119x over previous
//
#include <hip/hip_runtime.h>
#include <hip/hip_bf16.h>

#define T_SEQ 2048
#define C_DIM 1024
#define H_NUM 16
#define D_HEAD 64
#define B_BATCH 4
#define M_ROWS (B_BATCH * T_SEQ)  // 8192

typedef __attribute__((ext_vector_type(8))) short short8;
typedef __attribute__((ext_vector_type(4))) short short4v;
typedef __attribute__((ext_vector_type(4))) float float4v;
typedef __attribute__((ext_vector_type(4))) int int4v;

// global_load_lds: LDS dest = wave-uniform base + lane*16; global src is per-lane.
#define GLOAD_LDS16(gp, lp)                                                              \
    __builtin_amdgcn_global_load_lds(                                                    \
        (const __attribute__((address_space(1))) void*)(gp),                             \
        (__attribute__((address_space(3))) void*)(lp), 16, 0, 0)

static __device__ inline short f2bf(float f) {
    __hip_bfloat16 h = __float2bfloat16(f);
    return *reinterpret_cast<short*>(&h);
}

// ---------------- convert x (fp32 -> bf16), vectorized ----------------
__global__ void k_convert_x(const float* __restrict__ x, short* __restrict__ xb, int n4) {
    int i = blockIdx.x * blockDim.x + threadIdx.x;
    int stride = gridDim.x * blockDim.x;
    for (; i < n4; i += stride) {
        float4v v = reinterpret_cast<const float4v*>(x)[i];
        short4v o;
        o[0] = f2bf(v[0]); o[1] = f2bf(v[1]); o[2] = f2bf(v[2]); o[3] = f2bf(v[3]);
        reinterpret_cast<short4v*>(xb)[i] = o;
    }
}

// ---------------- transpose + convert W (K x N fp32 -> N x K bf16) ----------------
__global__ void k_transpose_w(const float* __restrict__ Wq, const float* __restrict__ Wk,
                              const float* __restrict__ Wv, const float* __restrict__ Wp,
                              short* __restrict__ out) {
    __shared__ float tile[32][33];
    const float* W = (blockIdx.z == 0) ? Wq : (blockIdx.z == 1) ? Wk : (blockIdx.z == 2) ? Wv : Wp;
    short* o = out + (size_t)blockIdx.z * C_DIM * C_DIM;
    int x = blockIdx.x * 32 + threadIdx.x;   // n (col of W)
    int y0 = blockIdx.y * 32;                // k base (row of W)
    for (int i = 0; i < 32; i += 8)
        tile[threadIdx.y + i][threadIdx.x] = W[(size_t)(y0 + threadIdx.y + i) * C_DIM + x];
    __syncthreads();
    int xo = y0 + threadIdx.x;               // k (contiguous in out)
    int yo0 = blockIdx.x * 32;               // n (row of out)
    for (int i = 0; i < 32; i += 8)
        o[(size_t)(yo0 + threadIdx.y + i) * C_DIM + xo] = f2bf(tile[threadIdx.x][threadIdx.y + i]);
}

// ---------------- fused QKV GEMM: 8192x1024 @ [Wq|Wk|Wv]^T (3072x1024) ----------------
// bn 0..7 -> Q (scaled 0.125*log2e, (B,H,T,D)); 8..15 -> K (B,H,T,D); 16..23 -> V^T (B,H,D,T)
__global__ __launch_bounds__(256) void k_gemm_qkv(const short* __restrict__ A,
                                                  const short* __restrict__ Bt,
                                                  const float* __restrict__ bq,
                                                  const float* __restrict__ bk,
                                                  const float* __restrict__ bv,
                                                  short* __restrict__ qo,
                                                  short* __restrict__ ko,
                                                  short* __restrict__ vo) {
    __shared__ short As[128][32];
    __shared__ short Bs[128][32];
    const int tid  = threadIdx.x;
    const int lane = tid & 63;
    const int w    = tid >> 6;
    const int wm   = w >> 1, wn = w & 1;
    const int bm   = blockIdx.y, bn = blockIdx.x;
    const int lrow = lane & 15;
    const int kgrp = lane >> 4;

    const int srow = lane >> 2;
    const int scol = (lane & 3) * 8;
    const short* gA = A  + (size_t)(bm * 128 + w * 32 + srow) * C_DIM + scol;
    const short* gB = Bt + (size_t)(bn * 128 + w * 32 + srow) * C_DIM + scol;
    short* lA0 = &As[w * 32][0];
    short* lA1 = &As[w * 32 + 16][0];
    short* lB0 = &Bs[w * 32][0];
    short* lB1 = &Bs[w * 32 + 16][0];

    float4v acc[4][4];
    const float4v fz = {0.f, 0.f, 0.f, 0.f};
    for (int i = 0; i < 4; ++i)
        for (int n = 0; n < 4; ++n) acc[i][n] = fz;

    for (int kt = 0; kt < C_DIM / 32; ++kt) {
        const int ko_ = kt * 32;
        GLOAD_LDS16(gA + ko_,               lA0);
        GLOAD_LDS16(gA + ko_ + 16 * C_DIM, lA1);
        GLOAD_LDS16(gB + ko_,               lB0);
        GLOAD_LDS16(gB + ko_ + 16 * C_DIM, lB1);
        __syncthreads();
        short8 af[4], bf[4];
#pragma unroll
        for (int i = 0; i < 4; ++i)
            af[i] = *reinterpret_cast<const short8*>(&As[wm * 64 + i * 16 + lrow][kgrp * 8]);
#pragma unroll
        for (int n = 0; n < 4; ++n)
            bf[n] = *reinterpret_cast<const short8*>(&Bs[wn * 64 + n * 16 + lrow][kgrp * 8]);
#pragma unroll
        for (int i = 0; i < 4; ++i)
#pragma unroll
            for (int n = 0; n < 4; ++n)
                acc[i][n] = __builtin_amdgcn_mfma_f32_16x16x32_bf16(af[i], bf[n], acc[i][n], 0, 0, 0);
        __syncthreads();
    }

    const int m = bn >> 3;                    // 0=Q 1=K 2=V (uniform per block)
    const float* bias = (m == 0) ? bq : (m == 1) ? bk : bv;
    short* o = (m == 0) ? qo : (m == 1) ? ko : vo;
    int cols[4];
    float bias_v[4];
#pragma unroll
    for (int n = 0; n < 4; ++n) {
        cols[n] = (bn & 7) * 128 + wn * 64 + n * 16 + lrow;   // 0..1023 within matrix
        bias_v[n] = bias[cols[n]];
    }
#pragma unroll
    for (int i = 0; i < 4; ++i) {
        int m0 = bm * 128 + wm * 64 + i * 16 + kgrp * 4;
#pragma unroll
        for (int n = 0; n < 4; ++n) {
            int hh = cols[n] >> 6, d = cols[n] & 63;
#pragma unroll
            for (int r = 0; r < 4; ++r) {
                float v = acc[i][n][r] + bias_v[n];
                int mm = m0 + r;
                int bidx = mm >> 11, t = mm & 2047;
                if (m == 0) v *= 0.18033688f;  // 0.125 * log2(e)
                size_t idx;
                if (m == 2)
                    idx = (((size_t)(bidx * H_NUM + hh)) * D_HEAD + d) * T_SEQ + t;
                else
                    idx = (((size_t)(bidx * H_NUM + hh)) * T_SEQ + t) * D_HEAD + d;
                o[idx] = f2bf(v);
            }
        }
    }
}

// ---------------- projection GEMM: y(8192x1024) @ Wp^T + bp -> fp32 out ----------------
__global__ __launch_bounds__(256) void k_gemm_proj(const short* __restrict__ A,
                                                   const short* __restrict__ Bt,
                                                   const float* __restrict__ bias,
                                                   float* __restrict__ outp) {
    __shared__ short As[128][32];
    __shared__ short Bs[128][32];
    const int tid  = threadIdx.x;
    const int lane = tid & 63;
    const int w    = tid >> 6;
    const int wm   = w >> 1, wn = w & 1;
    const int bm   = blockIdx.y, bn = blockIdx.x;
    const int lrow = lane & 15;
    const int kgrp = lane >> 4;

    const int srow = lane >> 2;
    const int scol = (lane & 3) * 8;
    const short* gA = A  + (size_t)(bm * 128 + w * 32 + srow) * C_DIM + scol;
    const short* gB = Bt + (size_t)(bn * 128 + w * 32 + srow) * C_DIM + scol;
    short* lA0 = &As[w * 32][0];
    short* lA1 = &As[w * 32 + 16][0];
    short* lB0 = &Bs[w * 32][0];
    short* lB1 = &Bs[w * 32 + 16][0];

    float4v acc[4][4];
    const float4v fz = {0.f, 0.f, 0.f, 0.f};
    for (int i = 0; i < 4; ++i)
        for (int n = 0; n < 4; ++n) acc[i][n] = fz;

    for (int kt = 0; kt < C_DIM / 32; ++kt) {
        const int ko_ = kt * 32;
        GLOAD_LDS16(gA + ko_,               lA0);
        GLOAD_LDS16(gA + ko_ + 16 * C_DIM, lA1);
        GLOAD_LDS16(gB + ko_,               lB0);
        GLOAD_LDS16(gB + ko_ + 16 * C_DIM, lB1);
        __syncthreads();
        short8 af[4], bf[4];
#pragma unroll
        for (int i = 0; i < 4; ++i)
            af[i] = *reinterpret_cast<const short8*>(&As[wm * 64 + i * 16 + lrow][kgrp * 8]);
#pragma unroll
        for (int n = 0; n < 4; ++n)
            bf[n] = *reinterpret_cast<const short8*>(&Bs[wn * 64 + n * 16 + lrow][kgrp * 8]);
#pragma unroll
        for (int i = 0; i < 4; ++i)
#pragma unroll
            for (int n = 0; n < 4; ++n)
                acc[i][n] = __builtin_amdgcn_mfma_f32_16x16x32_bf16(af[i], bf[n], acc[i][n], 0, 0, 0);
        __syncthreads();
    }

    int cols[4];
    float bias_v[4];
#pragma unroll
    for (int n = 0; n < 4; ++n) {
        cols[n] = bn * 128 + wn * 64 + n * 16 + lrow;
        bias_v[n] = bias[cols[n]];
    }
#pragma unroll
    for (int i = 0; i < 4; ++i) {
        int m0 = bm * 128 + wm * 64 + i * 16 + kgrp * 4;
#pragma unroll
        for (int n = 0; n < 4; ++n)
#pragma unroll
            for (int r = 0; r < 4; ++r)
                outp[(size_t)(m0 + r) * C_DIM + cols[n]] = acc[i][n][r] + bias_v[n];
    }
}

// ---------------- flash attention ----------------
// v4: v3 + software pipeline — QK MFMAs of tile t+1 issue between the P-LDS write and
// the PV of tile t (s regs are dead after the write, so QK(t+1) reuses them). The QK
// matrix-pipe latency hides the pa ds_read wait; softmax VALU of t+1 finds s ready.
__global__ __launch_bounds__(256) void k_attn(const short* __restrict__ qb,
                                              const short* __restrict__ kb,
                                              const short* __restrict__ vtb,
                                              short* __restrict__ yb) {
    __shared__ short p_lds[4][16][72];
    const int tid  = threadIdx.x;
    const int lane = tid & 63, w = tid >> 6;
    const int lrow = lane & 15, kgrp = lane >> 4;
    const int bh = blockIdx.y;
    const int b = bh >> 4, h = bh & 15;
    const float4v fz = {0.f, 0.f, 0.f, 0.f};
    const float THR = 8.0f;

#pragma unroll 1
    for (int phase = 0; phase < 2; ++phase) {
        const int qj = (phase == 0) ? (31 - (int)blockIdx.x) : (int)blockIdx.x;
        const int q0 = qj * 64;
        const int qrow = q0 + w * 16;

        short8 qf[2];
        {
            const short* qbase = qb + ((size_t)bh * T_SEQ + qrow + lrow) * D_HEAD + kgrp * 8;
            qf[0] = *reinterpret_cast<const short8*>(qbase);
            qf[1] = *reinterpret_cast<const short8*>(qbase + 32);
        }

        float m_r[4], l_p[4];
        float4v acc[4];
        float4v s[4];
        for (int r = 0; r < 4; ++r) { m_r[r] = -__builtin_huge_valf(); l_p[r] = 0.f; }
        for (int n = 0; n < 4; ++n) { acc[n] = fz; s[n] = fz; }

        const int ntiles = qj + 1;

        // prologue: S(0) = QK of tile 0
        {
            const short* kbase = kb + ((size_t)bh * T_SEQ + 0 + lrow) * D_HEAD + kgrp * 8;
#pragma unroll
            for (int n = 0; n < 4; ++n) {
                const short* kp = kbase + (size_t)n * 16 * D_HEAD;
                short8 kf0 = *reinterpret_cast<const short8*>(kp);
                short8 kf1 = *reinterpret_cast<const short8*>(kp + 32);
                s[n] = __builtin_amdgcn_mfma_f32_16x16x32_bf16(qf[0], kf0, s[n], 0, 0, 0);
                s[n] = __builtin_amdgcn_mfma_f32_16x16x32_bf16(qf[1], kf1, s[n], 0, 0, 0);
            }
        }

        for (int kt = 0; kt < ntiles; ++kt) {
            const int k0 = kt * 64;
            // V loads for tile kt — issue first, latency hides under softmax
            const short* vbase = vtb + ((size_t)bh * D_HEAD + lrow) * T_SEQ + k0 + kgrp * 8;
            short8 vf0[4], vf1[4];
#pragma unroll
            for (int n = 0; n < 4; ++n) {
                const short* vp = vbase + (size_t)n * 16 * T_SEQ;
                vf0[n] = *reinterpret_cast<const short8*>(vp);
                vf1[n] = *reinterpret_cast<const short8*>(vp + 32);
            }
            if (kt == ntiles - 1) {  // diagonal tile: causal mask
#pragma unroll
                for (int n = 0; n < 4; ++n) {
                    int kabs = k0 + n * 16 + lrow;
#pragma unroll
                    for (int r = 0; r < 4; ++r) {
                        int qabs = qrow + kgrp * 4 + r;
                        if (kabs > qabs) s[n][r] = -__builtin_huge_valf();
                    }
                }
            }
            // row max
            float tm[4];
#pragma unroll
            for (int r = 0; r < 4; ++r) {
                float t = fmaxf(fmaxf(s[0][r], s[1][r]), fmaxf(s[2][r], s[3][r]));
                t = fmaxf(t, __shfl_xor(t, 1));
                t = fmaxf(t, __shfl_xor(t, 2));
                t = fmaxf(t, __shfl_xor(t, 4));
                t = fmaxf(t, __shfl_xor(t, 8));
                tm[r] = t;
            }
            int grow = (tm[0] > m_r[0] + THR) | (tm[1] > m_r[1] + THR) |
                       (tm[2] > m_r[2] + THR) | (tm[3] > m_r[3] + THR);
            if (__any(grow)) {
#pragma unroll
                for (int r = 0; r < 4; ++r) {
                    float mnew = fmaxf(m_r[r], tm[r]);
                    float sc = exp2f(m_r[r] - mnew);
                    m_r[r] = mnew;
                    l_p[r] *= sc;
#pragma unroll
                    for (int n = 0; n < 4; ++n) acc[n][r] *= sc;
                }
            }
            // P = exp2(s - m), per-lane partial denom, write to wave-private LDS
#pragma unroll
            for (int n = 0; n < 4; ++n)
#pragma unroll
                for (int r = 0; r < 4; ++r) {
                    float p = exp2f(s[n][r] - m_r[r]);
                    l_p[r] += p;
                    p_lds[w][kgrp * 4 + r][n * 16 + lrow] = f2bf(p);
                }

            // pipeline: QK for tile kt+1 into s (dead after the writes above)
            if (kt + 1 < ntiles) {
                const short* kbase = kb + ((size_t)bh * T_SEQ + (kt + 1) * 64 + lrow) * D_HEAD + kgrp * 8;
#pragma unroll
                for (int n = 0; n < 4; ++n) {
                    const short* kp = kbase + (size_t)n * 16 * D_HEAD;
                    short8 kf0 = *reinterpret_cast<const short8*>(kp);
                    short8 kf1 = *reinterpret_cast<const short8*>(kp + 32);
                    float4v t = fz;
                    t = __builtin_amdgcn_mfma_f32_16x16x32_bf16(qf[0], kf0, t, 0, 0, 0);
                    t = __builtin_amdgcn_mfma_f32_16x16x32_bf16(qf[1], kf1, t, 0, 0, 0);
                    s[n] = t;
                }
            }

            // PV for tile kt
            short8 pa[2];
            pa[0] = *reinterpret_cast<const short8*>(&p_lds[w][lrow][kgrp * 8]);
            pa[1] = *reinterpret_cast<const short8*>(&p_lds[w][lrow][32 + kgrp * 8]);
#pragma unroll
            for (int n = 0; n < 4; ++n) {
                acc[n] = __builtin_amdgcn_mfma_f32_16x16x32_bf16(pa[0], vf0[n], acc[n], 0, 0, 0);
                acc[n] = __builtin_amdgcn_mfma_f32_16x16x32_bf16(pa[1], vf1[n], acc[n], 0, 0, 0);
            }
        }

        // final denom reduce + store
#pragma unroll
        for (int r = 0; r < 4; ++r) {
            float t = l_p[r];
            t += __shfl_xor(t, 1);
            t += __shfl_xor(t, 2);
            t += __shfl_xor(t, 4);
            t += __shfl_xor(t, 8);
            float inv = 1.0f / t;
            int trow = qrow + kgrp * 4 + r;
            size_t base = ((size_t)b * T_SEQ + trow) * C_DIM + h * D_HEAD;
#pragma unroll
            for (int n = 0; n < 4; ++n)
                yb[base + n * 16 + lrow] = f2bf(acc[n][r] * inv);
        }
    }
}

extern "C" void kernel_launch(void* const* d_in, const int* in_sizes, int n_in,
                              void* d_out, int out_size, void* d_ws, size_t ws_size,
                              hipStream_t stream) {
    const float* x  = (const float*)d_in[0];
    const float* Wq = (const float*)d_in[1];
    const float* bq = (const float*)d_in[2];
    const float* Wk = (const float*)d_in[3];
    const float* bk = (const float*)d_in[4];
    const float* Wv = (const float*)d_in[5];
    const float* bv = (const float*)d_in[6];
    const float* Wp = (const float*)d_in[7];
    const float* bp = (const float*)d_in[8];

    char* ws = (char*)d_ws;
    short* xb = (short*)(ws);                        // 16 MiB (reused as y after attention)
    short* wt = (short*)(ws + (size_t)(16 << 20));   // 8 MiB (Wq|Wk|Wv|Wp transposed bf16)
    short* qb = (short*)(ws + (size_t)(24 << 20));   // 16 MiB
    short* kb = (short*)(ws + (size_t)(40 << 20));   // 16 MiB
    short* vt = (short*)(ws + (size_t)(56 << 20));   // 16 MiB; total 72 MiB

    k_convert_x<<<2048, 256, 0, stream>>>(x, xb, M_ROWS * C_DIM / 4);
    k_transpose_w<<<dim3(32, 32, 4), dim3(32, 8), 0, stream>>>(Wq, Wk, Wv, Wp, wt);

    k_gemm_qkv<<<dim3(24, 64), 256, 0, stream>>>(xb, wt, bq, bk, bv, qb, kb, vt);

    k_attn<<<dim3(16, 64), 256, 0, stream>>>(qb, kb, vt, xb);

    k_gemm_proj<<<dim3(8, 64), 256, 0, stream>>>(xb, wt + (3u << 20), bp, (float*)d_out);
}

// Round 15
// 476.904 us; speedup vs baseline: 1.5031x; 1.0165x over previous
//
#include <hip/hip_runtime.h>
#include <hip/hip_bf16.h>

#define T_SEQ 2048
#define C_DIM 1024
#define H_NUM 16
#define D_HEAD 64
#define B_BATCH 4
#define M_ROWS (B_BATCH * T_SEQ)  // 8192

typedef __attribute__((ext_vector_type(8))) short short8;
typedef __attribute__((ext_vector_type(4))) short short4v;
typedef __attribute__((ext_vector_type(4))) float float4v;
typedef __attribute__((ext_vector_type(4))) int int4v;

// global_load_lds: LDS dest = wave-uniform base + lane*16; global src is per-lane.
#define GLOAD_LDS16(gp, lp)                                                              \
    __builtin_amdgcn_global_load_lds(                                                    \
        (const __attribute__((address_space(1))) void*)(gp),                             \
        (__attribute__((address_space(3))) void*)(lp), 16, 0, 0)

static __device__ inline short f2bf(float f) {
    __hip_bfloat16 h = __float2bfloat16(f);
    return *reinterpret_cast<short*>(&h);
}

// ---------------- convert x (fp32 -> bf16), vectorized ----------------
__global__ void k_convert_x(const float* __restrict__ x, short* __restrict__ xb, int n4) {
    int i = blockIdx.x * blockDim.x + threadIdx.x;
    int stride = gridDim.x * blockDim.x;
    for (; i < n4; i += stride) {
        float4v v = reinterpret_cast<const float4v*>(x)[i];
        short4v o;
        o[0] = f2bf(v[0]); o[1] = f2bf(v[1]); o[2] = f2bf(v[2]); o[3] = f2bf(v[3]);
        reinterpret_cast<short4v*>(xb)[i] = o;
    }
}

// ---------------- transpose + convert W (K x N fp32 -> N x K bf16) ----------------
__global__ void k_transpose_w(const float* __restrict__ Wq, const float* __restrict__ Wk,
                              const float* __restrict__ Wv, const float* __restrict__ Wp,
                              short* __restrict__ out) {
    __shared__ float tile[32][33];
    const float* W = (blockIdx.z == 0) ? Wq : (blockIdx.z == 1) ? Wk : (blockIdx.z == 2) ? Wv : Wp;
    short* o = out + (size_t)blockIdx.z * C_DIM * C_DIM;
    int x = blockIdx.x * 32 + threadIdx.x;   // n (col of W)
    int y0 = blockIdx.y * 32;                // k base (row of W)
    for (int i = 0; i < 32; i += 8)
        tile[threadIdx.y + i][threadIdx.x] = W[(size_t)(y0 + threadIdx.y + i) * C_DIM + x];
    __syncthreads();
    int xo = y0 + threadIdx.x;               // k (contiguous in out)
    int yo0 = blockIdx.x * 32;               // n (row of out)
    for (int i = 0; i < 32; i += 8)
        o[(size_t)(yo0 + threadIdx.y + i) * C_DIM + xo] = f2bf(tile[threadIdx.x][threadIdx.y + i]);
}

// ---------------- fused QKV GEMM: 8192x1024 @ [Wq|Wk|Wv]^T (3072x1024) ----------------
// bn 0..7 -> Q (scaled 0.125*log2e, (B,H,T,D)); 8..15 -> K (B,H,T,D); 16..23 -> V^T (B,H,D,T)
__global__ __launch_bounds__(256) void k_gemm_qkv(const short* __restrict__ A,
                                                  const short* __restrict__ Bt,
                                                  const float* __restrict__ bq,
                                                  const float* __restrict__ bk,
                                                  const float* __restrict__ bv,
                                                  short* __restrict__ qo,
                                                  short* __restrict__ ko,
                                                  short* __restrict__ vo) {
    __shared__ short As[128][32];
    __shared__ short Bs[128][32];
    const int tid  = threadIdx.x;
    const int lane = tid & 63;
    const int w    = tid >> 6;
    const int wm   = w >> 1, wn = w & 1;
    const int bm   = blockIdx.y, bn = blockIdx.x;
    const int lrow = lane & 15;
    const int kgrp = lane >> 4;

    const int srow = lane >> 2;
    const int scol = (lane & 3) * 8;
    const short* gA = A  + (size_t)(bm * 128 + w * 32 + srow) * C_DIM + scol;
    const short* gB = Bt + (size_t)(bn * 128 + w * 32 + srow) * C_DIM + scol;
    short* lA0 = &As[w * 32][0];
    short* lA1 = &As[w * 32 + 16][0];
    short* lB0 = &Bs[w * 32][0];
    short* lB1 = &Bs[w * 32 + 16][0];

    float4v acc[4][4];
    const float4v fz = {0.f, 0.f, 0.f, 0.f};
    for (int i = 0; i < 4; ++i)
        for (int n = 0; n < 4; ++n) acc[i][n] = fz;

    for (int kt = 0; kt < C_DIM / 32; ++kt) {
        const int ko_ = kt * 32;
        GLOAD_LDS16(gA + ko_,               lA0);
        GLOAD_LDS16(gA + ko_ + 16 * C_DIM, lA1);
        GLOAD_LDS16(gB + ko_,               lB0);
        GLOAD_LDS16(gB + ko_ + 16 * C_DIM, lB1);
        __syncthreads();
        short8 af[4], bf[4];
#pragma unroll
        for (int i = 0; i < 4; ++i)
            af[i] = *reinterpret_cast<const short8*>(&As[wm * 64 + i * 16 + lrow][kgrp * 8]);
#pragma unroll
        for (int n = 0; n < 4; ++n)
            bf[n] = *reinterpret_cast<const short8*>(&Bs[wn * 64 + n * 16 + lrow][kgrp * 8]);
#pragma unroll
        for (int i = 0; i < 4; ++i)
#pragma unroll
            for (int n = 0; n < 4; ++n)
                acc[i][n] = __builtin_amdgcn_mfma_f32_16x16x32_bf16(af[i], bf[n], acc[i][n], 0, 0, 0);
        __syncthreads();
    }

    const int m = bn >> 3;                    // 0=Q 1=K 2=V (uniform per block)
    const float* bias = (m == 0) ? bq : (m == 1) ? bk : bv;
    short* o = (m == 0) ? qo : (m == 1) ? ko : vo;
    int cols[4];
    float bias_v[4];
#pragma unroll
    for (int n = 0; n < 4; ++n) {
        cols[n] = (bn & 7) * 128 + wn * 64 + n * 16 + lrow;   // 0..1023 within matrix
        bias_v[n] = bias[cols[n]];
    }
#pragma unroll
    for (int i = 0; i < 4; ++i) {
        int m0 = bm * 128 + wm * 64 + i * 16 + kgrp * 4;
#pragma unroll
        for (int n = 0; n < 4; ++n) {
            int hh = cols[n] >> 6, d = cols[n] & 63;
#pragma unroll
            for (int r = 0; r < 4; ++r) {
                float v = acc[i][n][r] + bias_v[n];
                int mm = m0 + r;
                int bidx = mm >> 11, t = mm & 2047;
                if (m == 0) v *= 0.18033688f;  // 0.125 * log2(e)
                size_t idx;
                if (m == 2)
                    idx = (((size_t)(bidx * H_NUM + hh)) * D_HEAD + d) * T_SEQ + t;
                else
                    idx = (((size_t)(bidx * H_NUM + hh)) * T_SEQ + t) * D_HEAD + d;
                o[idx] = f2bf(v);
            }
        }
    }
}

// ---------------- projection GEMM: y(8192x1024) @ Wp^T + bp -> fp32 out ----------------
__global__ __launch_bounds__(256) void k_gemm_proj(const short* __restrict__ A,
                                                   const short* __restrict__ Bt,
                                                   const float* __restrict__ bias,
                                                   float* __restrict__ outp) {
    __shared__ short As[128][32];
    __shared__ short Bs[128][32];
    const int tid  = threadIdx.x;
    const int lane = tid & 63;
    const int w    = tid >> 6;
    const int wm   = w >> 1, wn = w & 1;
    const int bm   = blockIdx.y, bn = blockIdx.x;
    const int lrow = lane & 15;
    const int kgrp = lane >> 4;

    const int srow = lane >> 2;
    const int scol = (lane & 3) * 8;
    const short* gA = A  + (size_t)(bm * 128 + w * 32 + srow) * C_DIM + scol;
    const short* gB = Bt + (size_t)(bn * 128 + w * 32 + srow) * C_DIM + scol;
    short* lA0 = &As[w * 32][0];
    short* lA1 = &As[w * 32 + 16][0];
    short* lB0 = &Bs[w * 32][0];
    short* lB1 = &Bs[w * 32 + 16][0];

    float4v acc[4][4];
    const float4v fz = {0.f, 0.f, 0.f, 0.f};
    for (int i = 0; i < 4; ++i)
        for (int n = 0; n < 4; ++n) acc[i][n] = fz;

    for (int kt = 0; kt < C_DIM / 32; ++kt) {
        const int ko_ = kt * 32;
        GLOAD_LDS16(gA + ko_,               lA0);
        GLOAD_LDS16(gA + ko_ + 16 * C_DIM, lA1);
        GLOAD_LDS16(gB + ko_,               lB0);
        GLOAD_LDS16(gB + ko_ + 16 * C_DIM, lB1);
        __syncthreads();
        short8 af[4], bf[4];
#pragma unroll
        for (int i = 0; i < 4; ++i)
            af[i] = *reinterpret_cast<const short8*>(&As[wm * 64 + i * 16 + lrow][kgrp * 8]);
#pragma unroll
        for (int n = 0; n < 4; ++n)
            bf[n] = *reinterpret_cast<const short8*>(&Bs[wn * 64 + n * 16 + lrow][kgrp * 8]);
#pragma unroll
        for (int i = 0; i < 4; ++i)
#pragma unroll
            for (int n = 0; n < 4; ++n)
                acc[i][n] = __builtin_amdgcn_mfma_f32_16x16x32_bf16(af[i], bf[n], acc[i][n], 0, 0, 0);
        __syncthreads();
    }

    int cols[4];
    float bias_v[4];
#pragma unroll
    for (int n = 0; n < 4; ++n) {
        cols[n] = bn * 128 + wn * 64 + n * 16 + lrow;
        bias_v[n] = bias[cols[n]];
    }
#pragma unroll
    for (int i = 0; i < 4; ++i) {
        int m0 = bm * 128 + wm * 64 + i * 16 + kgrp * 4;
#pragma unroll
        for (int n = 0; n < 4; ++n)
#pragma unroll
            for (int r = 0; r < 4; ++r)
                outp[(size_t)(m0 + r) * C_DIM + cols[n]] = acc[i][n][r] + bias_v[n];
    }
}

// ---------------- flash attention ----------------
// v5: v4 + XCD-aware block remap. Linear bid -> (xcd = bid&7) owns bh in [xcd*8, xcd*8+8):
// per-XCD resident K/V working set drops 32MB -> 4MB (= L2 size), so K/V loads hit L2
// (~200cy) instead of HBM (~900cy). Pure bijective index remap; work unchanged.
__global__ __launch_bounds__(256) void k_attn(const short* __restrict__ qb,
                                              const short* __restrict__ kb,
                                              const short* __restrict__ vtb,
                                              short* __restrict__ yb) {
    __shared__ short p_lds[4][16][72];
    const int tid  = threadIdx.x;
    const int lane = tid & 63, w = tid >> 6;
    const int lrow = lane & 15, kgrp = lane >> 4;
    // XCD swizzle: grid is (16, 64) = 1024 blocks; HW round-robins linear bid over 8 XCDs.
    const int bid = (int)(blockIdx.y * gridDim.x + blockIdx.x);
    const int xcd = bid & 7;
    const int seq = bid >> 3;                 // 0..127 within XCD
    const int bh  = xcd * 8 + (seq & 7);      // 8 bh per XCD
    const int qx  = seq >> 3;                 // 0..15 q-pair index
    const int b = bh >> 4, h = bh & 15;
    const float4v fz = {0.f, 0.f, 0.f, 0.f};
    const float THR = 8.0f;

#pragma unroll 1
    for (int phase = 0; phase < 2; ++phase) {
        const int qj = (phase == 0) ? (31 - qx) : qx;
        const int q0 = qj * 64;
        const int qrow = q0 + w * 16;

        short8 qf[2];
        {
            const short* qbase = qb + ((size_t)bh * T_SEQ + qrow + lrow) * D_HEAD + kgrp * 8;
            qf[0] = *reinterpret_cast<const short8*>(qbase);
            qf[1] = *reinterpret_cast<const short8*>(qbase + 32);
        }

        float m_r[4], l_p[4];
        float4v acc[4];
        float4v s[4];
        for (int r = 0; r < 4; ++r) { m_r[r] = -__builtin_huge_valf(); l_p[r] = 0.f; }
        for (int n = 0; n < 4; ++n) { acc[n] = fz; s[n] = fz; }

        const int ntiles = qj + 1;

        // prologue: S(0) = QK of tile 0
        {
            const short* kbase = kb + ((size_t)bh * T_SEQ + 0 + lrow) * D_HEAD + kgrp * 8;
#pragma unroll
            for (int n = 0; n < 4; ++n) {
                const short* kp = kbase + (size_t)n * 16 * D_HEAD;
                short8 kf0 = *reinterpret_cast<const short8*>(kp);
                short8 kf1 = *reinterpret_cast<const short8*>(kp + 32);
                s[n] = __builtin_amdgcn_mfma_f32_16x16x32_bf16(qf[0], kf0, s[n], 0, 0, 0);
                s[n] = __builtin_amdgcn_mfma_f32_16x16x32_bf16(qf[1], kf1, s[n], 0, 0, 0);
            }
        }

        for (int kt = 0; kt < ntiles; ++kt) {
            const int k0 = kt * 64;
            // V loads for tile kt — issue first, latency hides under softmax
            const short* vbase = vtb + ((size_t)bh * D_HEAD + lrow) * T_SEQ + k0 + kgrp * 8;
            short8 vf0[4], vf1[4];
#pragma unroll
            for (int n = 0; n < 4; ++n) {
                const short* vp = vbase + (size_t)n * 16 * T_SEQ;
                vf0[n] = *reinterpret_cast<const short8*>(vp);
                vf1[n] = *reinterpret_cast<const short8*>(vp + 32);
            }
            if (kt == ntiles - 1) {  // diagonal tile: causal mask
#pragma unroll
                for (int n = 0; n < 4; ++n) {
                    int kabs = k0 + n * 16 + lrow;
#pragma unroll
                    for (int r = 0; r < 4; ++r) {
                        int qabs = qrow + kgrp * 4 + r;
                        if (kabs > qabs) s[n][r] = -__builtin_huge_valf();
                    }
                }
            }
            // row max
            float tm[4];
#pragma unroll
            for (int r = 0; r < 4; ++r) {
                float t = fmaxf(fmaxf(s[0][r], s[1][r]), fmaxf(s[2][r], s[3][r]));
                t = fmaxf(t, __shfl_xor(t, 1));
                t = fmaxf(t, __shfl_xor(t, 2));
                t = fmaxf(t, __shfl_xor(t, 4));
                t = fmaxf(t, __shfl_xor(t, 8));
                tm[r] = t;
            }
            int grow = (tm[0] > m_r[0] + THR) | (tm[1] > m_r[1] + THR) |
                       (tm[2] > m_r[2] + THR) | (tm[3] > m_r[3] + THR);
            if (__any(grow)) {
#pragma unroll
                for (int r = 0; r < 4; ++r) {
                    float mnew = fmaxf(m_r[r], tm[r]);
                    float sc = exp2f(m_r[r] - mnew);
                    m_r[r] = mnew;
                    l_p[r] *= sc;
#pragma unroll
                    for (int n = 0; n < 4; ++n) acc[n][r] *= sc;
                }
            }
            // P = exp2(s - m), per-lane partial denom, write to wave-private LDS
#pragma unroll
            for (int n = 0; n < 4; ++n)
#pragma unroll
                for (int r = 0; r < 4; ++r) {
                    float p = exp2f(s[n][r] - m_r[r]);
                    l_p[r] += p;
                    p_lds[w][kgrp * 4 + r][n * 16 + lrow] = f2bf(p);
                }

            // pipeline: QK for tile kt+1 into s (dead after the writes above)
            if (kt + 1 < ntiles) {
                const short* kbase = kb + ((size_t)bh * T_SEQ + (kt + 1) * 64 + lrow) * D_HEAD + kgrp * 8;
#pragma unroll
                for (int n = 0; n < 4; ++n) {
                    const short* kp = kbase + (size_t)n * 16 * D_HEAD;
                    short8 kf0 = *reinterpret_cast<const short8*>(kp);
                    short8 kf1 = *reinterpret_cast<const short8*>(kp + 32);
                    float4v t = fz;
                    t = __builtin_amdgcn_mfma_f32_16x16x32_bf16(qf[0], kf0, t, 0, 0, 0);
                    t = __builtin_amdgcn_mfma_f32_16x16x32_bf16(qf[1], kf1, t, 0, 0, 0);
                    s[n] = t;
                }
            }

            // PV for tile kt
            short8 pa[2];
            pa[0] = *reinterpret_cast<const short8*>(&p_lds[w][lrow][kgrp * 8]);
            pa[1] = *reinterpret_cast<const short8*>(&p_lds[w][lrow][32 + kgrp * 8]);
#pragma unroll
            for (int n = 0; n < 4; ++n) {
                acc[n] = __builtin_amdgcn_mfma_f32_16x16x32_bf16(pa[0], vf0[n], acc[n], 0, 0, 0);
                acc[n] = __builtin_amdgcn_mfma_f32_16x16x32_bf16(pa[1], vf1[n], acc[n], 0, 0, 0);
            }
        }

        // final denom reduce + store
#pragma unroll
        for (int r = 0; r < 4; ++r) {
            float t = l_p[r];
            t += __shfl_xor(t, 1);
            t += __shfl_xor(t, 2);
            t += __shfl_xor(t, 4);
            t += __shfl_xor(t, 8);
            float inv = 1.0f / t;
            int trow = qrow + kgrp * 4 + r;
            size_t base = ((size_t)b * T_SEQ + trow) * C_DIM + h * D_HEAD;
#pragma unroll
            for (int n = 0; n < 4; ++n)
                yb[base + n * 16 + lrow] = f2bf(acc[n][r] * inv);
        }
    }
}

extern "C" void kernel_launch(void* const* d_in, const int* in_sizes, int n_in,
                              void* d_out, int out_size, void* d_ws, size_t ws_size,
                              hipStream_t stream) {
    const float* x  = (const float*)d_in[0];
    const float* Wq = (const float*)d_in[1];
    const float* bq = (const float*)d_in[2];
    const float* Wk = (const float*)d_in[3];
    const float* bk = (const float*)d_in[4];
    const float* Wv = (const float*)d_in[5];
    const float* bv = (const float*)d_in[6];
    const float* Wp = (const float*)d_in[7];
    const float* bp = (const float*)d_in[8];

    char* ws = (char*)d_ws;
    short* xb = (short*)(ws);                        // 16 MiB (reused as y after attention)
    short* wt = (short*)(ws + (size_t)(16 << 20));   // 8 MiB (Wq|Wk|Wv|Wp transposed bf16)
    short* qb = (short*)(ws + (size_t)(24 << 20));   // 16 MiB
    short* kb = (short*)(ws + (size_t)(40 << 20));   // 16 MiB
    short* vt = (short*)(ws + (size_t)(56 << 20));   // 16 MiB; total 72 MiB

    k_convert_x<<<2048, 256, 0, stream>>>(x, xb, M_ROWS * C_DIM / 4);
    k_transpose_w<<<dim3(32, 32, 4), dim3(32, 8), 0, stream>>>(Wq, Wk, Wv, Wp, wt);

    k_gemm_qkv<<<dim3(24, 64), 256, 0, stream>>>(xb, wt, bq, bk, bv, qb, kb, vt);

    k_attn<<<dim3(16, 64), 256, 0, stream>>>(qb, kb, vt, xb);

    k_gemm_proj<<<dim3(8, 64), 256, 0, stream>>>(xb, wt + (3u << 20), bp, (float*)d_out);
}